// Round 1
// 75.362 us; speedup vs baseline: 1.0499x; 1.0499x over previous
//
#include <hip/hip_runtime.h>

// Problem constants: B=128, IN=256, H=128, OUT=32
#define B_   128
#define IN_  256
#define H_   128
#define OUT_ 32
#define HT   2                 // h per block (was 4): doubles grid -> 4 blocks/CU
#define BT   8                 // b per block
#define NHB  (H_ / HT)         // 64 h-blocks
#define NBB  (B_ / BT)         // 16 b-blocks
// diff2 row: 256 i * 8 b, +8 pad every 16 i so ig rotates LDS banks (16*136=2176), +8 tail
#define DIFF_STRIDE 2184
#define SM_FLOATS   8192       // phase-3 red needs 16*512; phase-1 uses 2*2184=4368 (aliased)

// grid (NHB, NBB) = (64,16) = 1024 blocks, 256 threads -> 4 blocks/CU, 16 waves/CU.
// Thread map (phase 2): ig = tid>>4 (i-chunk of 16), hl = (tid>>3)&1, og = tid&7 (o4 = og*4).
__global__ __launch_bounds__(256, 4) void o2_main(
    const float* __restrict__ input,      // (B, IN)
    const float* __restrict__ sigma_psi,  // (IN, H, OUT)
    const float* __restrict__ chi,        // (IN, H)
    const float* __restrict__ sigma_eps,  // (H, OUT)
    const float* __restrict__ eta,        // (H, OUT)
    float* __restrict__ sw_part,          // (NHB, B, OUT)
    float* __restrict__ swe_part)         // (NHB, B, OUT)
{
    const int tid = threadIdx.x;
    const int og = tid & 7;
    const int hl = (tid >> 3) & 1;
    const int ig = tid >> 4;              // 0..15
    const int hb = blockIdx.x;
    const int h_base = hb * HT;
    const int b_base = blockIdx.y * BT;

    __shared__ __align__(16) float sm[SM_FLOATS];

    // Phase 1: thread t owns i = t. 1 float2 chi load + 8 coalesced input loads
    // (lanes = consecutive i -> 256B contiguous per load), full register reuse:
    // 9 VMEM/thread vs 64 in the previous version.
    {
        const int i = tid;
        const float2 c2 = *(const float2*)(chi + i * H_ + h_base);
        float xv[8];
#pragma unroll
        for (int b = 0; b < 8; ++b)
            xv[b] = input[(b_base + b) * IN_ + i];
        const int ioff = i * 8 + (i >> 4) * 8;   // pad 8 words per 16-i group
#pragma unroll
        for (int hh = 0; hh < HT; ++hh) {
            const float c = (hh == 0) ? c2.x : c2.y;
            float4 w0, w1; float e;
            e = c - xv[0]; w0.x = e * e;
            e = c - xv[1]; w0.y = e * e;
            e = c - xv[2]; w0.z = e * e;
            e = c - xv[3]; w0.w = e * e;
            e = c - xv[4]; w1.x = e * e;
            e = c - xv[5]; w1.y = e * e;
            e = c - xv[6]; w1.z = e * e;
            e = c - xv[7]; w1.w = e * e;
            float* dst = sm + hh * DIFF_STRIDE + ioff;
            *(float4*)dst       = w0;            // b = 0..3
            *(float4*)(dst + 4) = w1;            // b = 4..7
        }
    }
    __syncthreads();

    // Phase 2: s[b][j] += sigma_psi^2 * diff2 over this thread's 16 i's
    const float* sp_ptr = sigma_psi + (size_t)(h_base + hl) * OUT_ + og * 4;
    const float* drow = sm + hl * DIFF_STRIDE + ig * 136;   // 16*8 + 8 pad per chunk
    float s[BT][4];
#pragma unroll
    for (int b = 0; b < BT; ++b) {
        s[b][0] = 0.f; s[b][1] = 0.f; s[b][2] = 0.f; s[b][3] = 0.f;
    }

#pragma unroll 4
    for (int k = 0; k < 16; ++k) {
        const int i = ig * 16 + k;
        float4 sp = *(const float4*)(sp_ptr + (size_t)i * (H_ * OUT_));
        float4 sp2;
        sp2.x = sp.x * sp.x; sp2.y = sp.y * sp.y;
        sp2.z = sp.z * sp.z; sp2.w = sp.w * sp.w;
        const float4* dp = (const float4*)(drow + k * 8);
        float4 eA = dp[0];                  // b = 0..3
        float4 eB = dp[1];                  // b = 4..7
        float ev[8] = {eA.x, eA.y, eA.z, eA.w, eB.x, eB.y, eB.z, eB.w};
#pragma unroll
        for (int b = 0; b < BT; ++b) {
            s[b][0] = fmaf(sp2.x, ev[b], s[b][0]);
            s[b][1] = fmaf(sp2.y, ev[b], s[b][1]);
            s[b][2] = fmaf(sp2.z, ev[b], s[b][2]);
            s[b][3] = fmaf(sp2.w, ev[b], s[b][3]);
        }
    }

    // Phase 3: tree-reduce over the 16 i-chunks (alias sm as red[ig][512])
    __syncthreads();
#pragma unroll
    for (int b = 0; b < BT; ++b) {
        float4 v; v.x = s[b][0]; v.y = s[b][1]; v.z = s[b][2]; v.w = s[b][3];
        *(float4*)(sm + ig * 512 + hl * 256 + b * 32 + og * 4) = v;
    }
    __syncthreads();

    // Phase 4: each thread owns one (b,o) bin; sum over ig, apply w, reduce over hh
    const int rb = tid >> 5;
    const int ro = tid & 31;
    float sw = 0.0f, swe = 0.0f;
#pragma unroll
    for (int hh = 0; hh < HT; ++hh) {
        float sfull = 0.0f;
#pragma unroll
        for (int g = 0; g < 16; ++g)
            sfull += sm[g * 512 + hh * 256 + rb * 32 + ro];
        const float se = sigma_eps[(h_base + hh) * OUT_ + ro];
        const float w = 1.0f / fmaf(se, se, sfull);
        sw += w;
        swe += w * eta[(h_base + hh) * OUT_ + ro];
    }
    const size_t po = ((size_t)hb * B_ + (b_base + rb)) * OUT_ + ro;
    sw_part[po]  = sw;
    swe_part[po] = swe;
}

// Final: reduce the 64 h-block partials per (b,o) bin and apply the posterior.
// 4-way split of the hb loop per bin; quad reduce via shfl_xor. 64 blocks x 256.
__global__ __launch_bounds__(256) void o2_final(
    const float* __restrict__ sw_part,
    const float* __restrict__ swe_part,
    const float* __restrict__ mu_phi,     // (OUT)
    const float* __restrict__ sigma_phi,  // (OUT)
    float* __restrict__ out)              // post_mu (B*OUT) then post_sigma2 (B*OUT)
{
    const int g = blockIdx.x * 256 + threadIdx.x;   // 16384 threads
    const int bin = g >> 2;                          // b*OUT + o
    const int q = g & 3;                             // hb quarter
    float sw = 0.0f, swe = 0.0f;
#pragma unroll
    for (int k = 0; k < NHB / 4; ++k) {
        const int hb = q * (NHB / 4) + k;
        sw  += sw_part[hb * (B_ * OUT_) + bin];
        swe += swe_part[hb * (B_ * OUT_) + bin];
    }
    // quads are adjacent lanes: reduce within quad
    sw  += __shfl_xor(sw, 1);   swe += __shfl_xor(swe, 1);
    sw  += __shfl_xor(sw, 2);   swe += __shfl_xor(swe, 2);
    if (q == 0) {
        const int o = bin & (OUT_ - 1);
        const float sp = sigma_phi[o];
        const float sp2 = sp * sp;
        const float inv = 1.0f / fmaf(sp2, sw, 1.0f);
        out[bin] = fmaf(sp2, swe, mu_phi[o]) * inv;   // post_mu
        out[B_ * OUT_ + bin] = sp2 * inv;             // post_sigma2
    }
}

extern "C" void kernel_launch(void* const* d_in, const int* in_sizes, int n_in,
                              void* d_out, int out_size, void* d_ws, size_t ws_size,
                              hipStream_t stream) {
    const float* input     = (const float*)d_in[0];
    const float* sigma_psi = (const float*)d_in[1];
    const float* chi       = (const float*)d_in[2];
    const float* sigma_eps = (const float*)d_in[3];
    const float* eta       = (const float*)d_in[4];
    const float* mu_phi    = (const float*)d_in[5];
    const float* sigma_phi = (const float*)d_in[6];
    float* out = (float*)d_out;
    float* ws  = (float*)d_ws;

    float* sw_part  = ws;                          // NHB*B*OUT floats (1 MB)
    float* swe_part = ws + NHB * B_ * OUT_;        // NHB*B*OUT floats

    dim3 grid(NHB, NBB);
    o2_main<<<grid, 256, 0, stream>>>(input, sigma_psi, chi, sigma_eps, eta,
                                      sw_part, swe_part);
    o2_final<<<(B_ * OUT_ * 4) / 256, 256, 0, stream>>>(sw_part, swe_part,
                                                        mu_phi, sigma_phi, out);
}